// Round 4
// baseline (81.185 us; speedup 1.0000x reference)
//
#include <hip/hip_runtime.h>
#include <stdint.h>

// ALCOVE RBF: out[b,e] = exp(-C * sum_d attn[d] * |E[e,d] - X[b,d]|)
// BATCH=2048, NE=2048, ND=128, f32 in/out.
//
// R6: ABLATION PROBE. Identical to R5 except the inner SAD loop runs TWICE
// (acc accumulates exactly 2x) and KEXP is halved -> output mathematically
// identical. Purpose: measure the inner loop's true marginal cost.
//   dur(R6) - dur(R5) = one extra inner pass (64 iter-slots).
// Cross-round fit (R2 vs R5, identical per-iter composition) says the inner
// loop is only ~8 us of the ~32 us kernel and ~24 us is structure-invariant
// "F" (staging/epilogue/launch) that bottom-up accounting can't explain.
// This probe decides whether R7 targets F or the inner loop.
//
// Numerics: acc doubles -> max 1.68e7 < 2^32 (no overflow); u32->f32 cvt
// error <= 1 ulp ~ 1e-6 on dist (negligible). Output = exp((KEXP/2)*2*acc),
// same as R5 to FP rounding.
//
// Quantization (R5): q(v) = (u16)(v*attn_d*2^19 + (2^15 + 0.5)), 2 dims per
// u32 word, v_sad_u16 = packed 2x16 |a-b|+c.

#define BATCH 2048
#define NE 2048
#define ND 128

#define TB 64    // batch tile
#define TE 64    // exemplar tile
#define ND2 64   // packed words per row (ND/2)

#define QSCALE 524288.0f              // 2^19
#define QBIAS  32768.5f               // 2^15 + 0.5
#define KEXP2  (-6.5f / 1048576.0f)   // -C / 2^20  (acc counted twice)

#define SAD16(acc, a, b) asm("v_sad_u16 %0, %1, %2, %0" : "+v"(acc) : "v"(a), "v"(b))

__global__ __launch_bounds__(256, 4)
void alcove_rbf_kernel(const float* __restrict__ X,
                       const float* __restrict__ E,
                       const float* __restrict__ A,
                       float* __restrict__ out) {
  __shared__ uint32_t Xs[ND2 * TB];  // [d2][b]  16 KB
  __shared__ uint32_t Es[ND2 * TE];  // [d2][e]  16 KB

  const int tid = (int)threadIdx.x;
  const int e0 = (int)blockIdx.x * TE;
  const int b0 = (int)blockIdx.y * TB;

  const int tx = tid & 15;          // e dir: 4 e's (4*tx..+3)
  const int ty = tid >> 4;          // b dir: 4 b's (4*ty..+3)
  const int lane_in = tid & 3;
  const int srow = tid >> 2;        // staging row 0..63

  uint32_t acc[4][4];
#pragma unroll
  for (int j = 0; j < 4; ++j)
#pragma unroll
    for (int i = 0; i < 4; ++i) acc[j][i] = 0u;

  // ---- stage ALL 128 dims once. Per it: 64 rows x 4 float4 cols.
  const float4* A4 = (const float4*)A;
#pragma unroll
  for (int it = 0; it < 8; ++it) {
    const int c4 = 4 * it + lane_in;   // float4 column 0..31
    const float4 a = A4[c4];
    const float sx = a.x * QSCALE, sy = a.y * QSCALE,
                sz = a.z * QSCALE, sw = a.w * QSCALE;
    const float4 vx = *(const float4*)(X + (size_t)(b0 + srow) * ND + 4 * c4);
    const float4 ve = *(const float4*)(E + (size_t)(e0 + srow) * ND + 4 * c4);

    const uint32_t x0 = ((uint32_t)fmaf(vx.x, sx, QBIAS)) |
                        (((uint32_t)fmaf(vx.y, sy, QBIAS)) << 16);
    const uint32_t x1 = ((uint32_t)fmaf(vx.z, sz, QBIAS)) |
                        (((uint32_t)fmaf(vx.w, sw, QBIAS)) << 16);
    const uint32_t e0w = ((uint32_t)fmaf(ve.x, sx, QBIAS)) |
                         (((uint32_t)fmaf(ve.y, sy, QBIAS)) << 16);
    const uint32_t e1w = ((uint32_t)fmaf(ve.z, sz, QBIAS)) |
                         (((uint32_t)fmaf(ve.w, sw, QBIAS)) << 16);

    Xs[(2 * c4 + 0) * TB + srow] = x0;
    Xs[(2 * c4 + 1) * TB + srow] = x1;
    Es[(2 * c4 + 0) * TE + srow] = e0w;
    Es[(2 * c4 + 1) * TE + srow] = e1w;
  }
  __syncthreads();

  // ---- inner loop, executed TWICE (ablation: marginal cost of one pass).
  const uint4* Xs4 = (const uint4*)Xs;
  const uint4* Es4 = (const uint4*)Es;
#pragma unroll 1
  for (int pass = 0; pass < 2; ++pass) {
#pragma unroll 8
    for (int d2 = 0; d2 < ND2; ++d2) {
      const uint4 xv = Xs4[d2 * (TB / 4) + ty];
      const uint4 ev = Es4[d2 * (TE / 4) + tx];
      SAD16(acc[0][0], xv.x, ev.x); SAD16(acc[0][1], xv.x, ev.y);
      SAD16(acc[0][2], xv.x, ev.z); SAD16(acc[0][3], xv.x, ev.w);
      SAD16(acc[1][0], xv.y, ev.x); SAD16(acc[1][1], xv.y, ev.y);
      SAD16(acc[1][2], xv.y, ev.z); SAD16(acc[1][3], xv.y, ev.w);
      SAD16(acc[2][0], xv.z, ev.x); SAD16(acc[2][1], xv.z, ev.y);
      SAD16(acc[2][2], xv.z, ev.z); SAD16(acc[2][3], xv.z, ev.w);
      SAD16(acc[3][0], xv.w, ev.x); SAD16(acc[3][1], xv.w, ev.y);
      SAD16(acc[3][2], xv.w, ev.z); SAD16(acc[3][3], xv.w, ev.w);
    }
  }

  // ---- epilogue: out = exp(KEXP2 * acc), 16B coalesced stores.
#pragma unroll
  for (int j = 0; j < 4; ++j) {
    const int b = b0 + 4 * ty + j;
    float4 o;
    o.x = __expf(KEXP2 * (float)acc[j][0]);
    o.y = __expf(KEXP2 * (float)acc[j][1]);
    o.z = __expf(KEXP2 * (float)acc[j][2]);
    o.w = __expf(KEXP2 * (float)acc[j][3]);
    reinterpret_cast<float4*>(out + (size_t)b * NE + e0)[tx] = o;
  }
}

extern "C" void kernel_launch(void* const* d_in, const int* in_sizes, int n_in,
                              void* d_out, int out_size, void* d_ws, size_t ws_size,
                              hipStream_t stream) {
  const float* X = (const float*)d_in[0];   // inputs    (2048,128)
  const float* E = (const float*)d_in[1];   // exemplars (2048,128)
  const float* A = (const float*)d_in[2];   // attn      (128,)
  float* out = (float*)d_out;               // (2048,2048)

  dim3 grid(NE / TE, BATCH / TB);           // (32,32) = 1024 blocks = 4/CU
  dim3 block(256);
  alcove_rbf_kernel<<<grid, block, 0, stream>>>(X, E, A, out);
}

// Round 6
// 73.361 us; speedup vs baseline: 1.1066x; 1.1066x over previous
//
#include <hip/hip_runtime.h>
#include <stdint.h>

// ALCOVE RBF: out[b,e] = exp(-C * sum_d attn[d] * |E[e,d] - X[b,d]|)
// BATCH=2048, NE=2048, ND=128, f32 in/out.
//
// R7b = R5 + three zero-risk F-phase levers (inner loop untouched):
//  1. XCD-aware chunked block swizzle (T1): each XCD gets 128 consecutive
//     tiles = 4 full b-rows x 32 e-tiles -> X slice (128 KB) and E (2 MB)
//     both L2-resident per XCD during the staging burst.
//  2. Non-temporal output stores (via native ext_vector type -- HIP float4
//     is a class and the builtin rejects it): 16 MB write-once stream,
//     skip L2 allocate/evict churn against the staged inputs.
//  3. exp2f epilogue: out = exp2(K2*acc), K2 = -C*log2e/2^19 -> one mul
//     + one transcendental per element (drops 16 v_mul/thread).
//
// Measured ledger (R6 ablation): inner loop = 7.3 us, F = ~25 us
// structure-invariant. Inner is within ~2x of the concurrent two-pipe
// floor; re-blocking moves cost more pipe-cycles than they reclaim
// (R3/R4 evidence), so R7 targets only locality/traffic in the F phase.
//
// Quantization (R5): attn >= 0 so attn_d*|x-e| == |attn_d*x - attn_d*e|.
//   q(v) = (u16)(v*attn_d*2^19 + (2^15 + 0.5)), 2 dims per u32 word,
//   v_sad_u16 = packed 2x16 |a-b|+c. dist err ~4e-5 -> out err ~3e-4.

#define BATCH 2048
#define NE 2048
#define ND 128

#define TB 64    // batch tile
#define TE 64    // exemplar tile
#define ND2 64   // packed words per row (ND/2)

#define QSCALE 524288.0f              // 2^19
#define QBIAS  32768.5f               // 2^15 + 0.5 (trunc -> round)
// out = exp(-C*acc/2^19) = exp2(K2*acc)
#define K2 (-6.5f * 1.4426950408889634f / 524288.0f)

#define SAD16(acc, a, b) asm("v_sad_u16 %0, %1, %2, %0" : "+v"(acc) : "v"(a), "v"(b))

typedef float vfloat4 __attribute__((ext_vector_type(4)));

__global__ __launch_bounds__(256, 4)
void alcove_rbf_kernel(const float* __restrict__ X,
                       const float* __restrict__ E,
                       const float* __restrict__ A,
                       float* __restrict__ out) {
  __shared__ uint32_t Xs[ND2 * TB];  // [d2][b]  16 KB
  __shared__ uint32_t Es[ND2 * TE];  // [d2][e]  16 KB

  const int tid = (int)threadIdx.x;

  // XCD-chunked swizzle: bid 0..1023; 1024 % 8 == 0 -> simple bijective form.
  // XCD k owns swz in [k*128, (k+1)*128) = 4 full b-tile rows x 32 e-tiles.
  const int bid = (int)blockIdx.y * 32 + (int)blockIdx.x;
  const int swz = (bid & 7) * 128 + (bid >> 3);
  const int e0 = (swz & 31) * TE;
  const int b0 = (swz >> 5) * TB;

  const int tx = tid & 15;          // e dir: 4 e's (4*tx..+3)
  const int ty = tid >> 4;          // b dir: 4 b's (4*ty..+3)
  const int lane_in = tid & 3;
  const int srow = tid >> 2;        // staging row 0..63

  uint32_t acc[4][4];
#pragma unroll
  for (int j = 0; j < 4; ++j)
#pragma unroll
    for (int i = 0; i < 4; ++i) acc[j][i] = 0u;

  // ---- stage ALL 128 dims once. Per it: 64 rows x 4 float4 cols.
  // Consecutive lanes take consecutive float4s of one row (64B coalesced).
  // LDS writes: bank = srow%32 -> 4-way conflict (32 writes/thread, ~2%).
  const float4* A4 = (const float4*)A;
#pragma unroll
  for (int it = 0; it < 8; ++it) {
    const int c4 = 4 * it + lane_in;   // float4 column 0..31
    const float4 a = A4[c4];
    const float sx = a.x * QSCALE, sy = a.y * QSCALE,
                sz = a.z * QSCALE, sw = a.w * QSCALE;
    const float4 vx = *(const float4*)(X + (size_t)(b0 + srow) * ND + 4 * c4);
    const float4 ve = *(const float4*)(E + (size_t)(e0 + srow) * ND + 4 * c4);

    const uint32_t x0 = ((uint32_t)fmaf(vx.x, sx, QBIAS)) |
                        (((uint32_t)fmaf(vx.y, sy, QBIAS)) << 16);
    const uint32_t x1 = ((uint32_t)fmaf(vx.z, sz, QBIAS)) |
                        (((uint32_t)fmaf(vx.w, sw, QBIAS)) << 16);
    const uint32_t e0w = ((uint32_t)fmaf(ve.x, sx, QBIAS)) |
                         (((uint32_t)fmaf(ve.y, sy, QBIAS)) << 16);
    const uint32_t e1w = ((uint32_t)fmaf(ve.z, sz, QBIAS)) |
                         (((uint32_t)fmaf(ve.w, sw, QBIAS)) << 16);

    Xs[(2 * c4 + 0) * TB + srow] = x0;
    Xs[(2 * c4 + 1) * TB + srow] = x1;
    Es[(2 * c4 + 0) * TE + srow] = e0w;
    Es[(2 * c4 + 1) * TE + srow] = e1w;
  }
  __syncthreads();

  // ---- inner loop: 64 d2-iters, 2 ds_read_b128 + 16 v_sad_u16 each.
  // Xs4: 4 distinct addrs/wave (16-lane broadcast) -> free.
  // Es4: 16 consecutive uint4s; tx vs tx+8 alias = 2-way -> free.
  const uint4* Xs4 = (const uint4*)Xs;
  const uint4* Es4 = (const uint4*)Es;
#pragma unroll 8
  for (int d2 = 0; d2 < ND2; ++d2) {
    const uint4 xv = Xs4[d2 * (TB / 4) + ty];
    const uint4 ev = Es4[d2 * (TE / 4) + tx];
    SAD16(acc[0][0], xv.x, ev.x); SAD16(acc[0][1], xv.x, ev.y);
    SAD16(acc[0][2], xv.x, ev.z); SAD16(acc[0][3], xv.x, ev.w);
    SAD16(acc[1][0], xv.y, ev.x); SAD16(acc[1][1], xv.y, ev.y);
    SAD16(acc[1][2], xv.y, ev.z); SAD16(acc[1][3], xv.y, ev.w);
    SAD16(acc[2][0], xv.z, ev.x); SAD16(acc[2][1], xv.z, ev.y);
    SAD16(acc[2][2], xv.z, ev.z); SAD16(acc[2][3], xv.z, ev.w);
    SAD16(acc[3][0], xv.w, ev.x); SAD16(acc[3][1], xv.w, ev.y);
    SAD16(acc[3][2], xv.w, ev.z); SAD16(acc[3][3], xv.w, ev.w);
  }

  // ---- epilogue: out = exp2(K2*acc); non-temporal 16B coalesced stores.
#pragma unroll
  for (int j = 0; j < 4; ++j) {
    const int b = b0 + 4 * ty + j;
    vfloat4 o;
    o.x = exp2f(K2 * (float)acc[j][0]);
    o.y = exp2f(K2 * (float)acc[j][1]);
    o.z = exp2f(K2 * (float)acc[j][2]);
    o.w = exp2f(K2 * (float)acc[j][3]);
    vfloat4* dst = reinterpret_cast<vfloat4*>(out + (size_t)b * NE + e0) + tx;
    __builtin_nontemporal_store(o, dst);
  }
}

extern "C" void kernel_launch(void* const* d_in, const int* in_sizes, int n_in,
                              void* d_out, int out_size, void* d_ws, size_t ws_size,
                              hipStream_t stream) {
  const float* X = (const float*)d_in[0];   // inputs    (2048,128)
  const float* E = (const float*)d_in[1];   // exemplars (2048,128)
  const float* A = (const float*)d_in[2];   // attn      (128,)
  float* out = (float*)d_out;               // (2048,2048)

  dim3 grid(NE / TE, BATCH / TB);           // (32,32) = 1024 blocks = 4/CU
  dim3 block(256);
  alcove_rbf_kernel<<<grid, block, 0, stream>>>(X, E, A, out);
}